// Round 11
// baseline (41.266 us; speedup 1.0000x reference)
//
#include <hip/hip_runtime.h>
#include <math.h>

// x: (16,3,448,448) fp32; 14x14 patches -> Hp=Wp=32; 3x3 DCT over 12x12 sliding windows
// out: (16,32,32) fp32
//
// Kernel A (rich_pc_kernel): block = 8 patches x ONE channel, 192 threads, grid 6144.
// Each thread: exactly one half-row run of 6 windows (192 runs = 8pc x 24) + 2 hist
// float4s (+8-thread tail). ~2-3 resident block-generations per CU (LDS ~3KB,
// VGPR<=64) -> block-level memory phases hide under other blocks' compute.
// Per-pc richness -> d_ws; Kernel B averages the 3 channels into out.
// Fallback (ws too small): r9's proven single-kernel path (38.6us).
//
// r10 bug fixed here: tail hist quads are rem 20..27 -> colT=(20+tid)*4 (was 16+tid).

typedef unsigned int uint32;

__device__ __forceinline__ float fsqrt_fast(float x) { return __builtin_amdgcn_sqrtf(x); } // v_sqrt_f32
__device__ __forceinline__ float frcp_fast(float x)  { return __builtin_amdgcn_rcpf(x);  } // v_rcp_f32
__device__ __forceinline__ float flog2_fast(float x) { return __builtin_amdgcn_logf(x);  } // v_log_f32

__device__ __forceinline__ float std3_fast(float a, float b, float c) {
    // ddof=0 std of 3 via E[x^2]-E[x]^2 (clamped)
    float s = a + b + c;
    float q = fmaf(a, a, fmaf(b, b, c * c));
    float v = fmaf(q, (1.0f / 3.0f), (s * s) * (-1.0f / 9.0f));
    return fsqrt_fast(fmaxf(v, 0.0f));
}

struct RunData {
    float2 a0, a1, a2, a3, b0, b1, b2, b3, c0, c1, c2, c3;
};

__device__ __forceinline__ RunData load_run(const float* base) {
    RunData r;
    r.a0 = *reinterpret_cast<const float2*>(base + 0);
    r.a1 = *reinterpret_cast<const float2*>(base + 2);
    r.a2 = *reinterpret_cast<const float2*>(base + 4);
    r.a3 = *reinterpret_cast<const float2*>(base + 6);
    r.b0 = *reinterpret_cast<const float2*>(base + 448);
    r.b1 = *reinterpret_cast<const float2*>(base + 450);
    r.b2 = *reinterpret_cast<const float2*>(base + 452);
    r.b3 = *reinterpret_cast<const float2*>(base + 454);
    r.c0 = *reinterpret_cast<const float2*>(base + 896);
    r.c1 = *reinterpret_cast<const float2*>(base + 898);
    r.c2 = *reinterpret_cast<const float2*>(base + 900);
    r.c3 = *reinterpret_cast<const float2*>(base + 902);
    return r;
}

__device__ __forceinline__ float run_psi(const RunData& rd, float k0, float k1, float k2) {
    float r0[8] = { rd.a0.x, rd.a0.y, rd.a1.x, rd.a1.y, rd.a2.x, rd.a2.y, rd.a3.x, rd.a3.y };
    float r1[8] = { rd.b0.x, rd.b0.y, rd.b1.x, rd.b1.y, rd.b2.x, rd.b2.y, rd.b3.x, rd.b3.y };
    float r2[8] = { rd.c0.x, rd.c0.y, rd.c1.x, rd.c1.y, rd.c2.x, rd.c2.y, rd.c3.x, rd.c3.y };

    float t0[8], t1[8], t2[8];
#pragma unroll
    for (int J = 0; J < 8; ++J) {
        float s = r0[J] + r2[J];
        t0[J] = k0 * (s + r1[J]);
        t1[J] = k1 * (r0[J] - r2[J]);
        t2[J] = k2 * fmaf(-2.0f, r1[J], s);
    }

    float psi_run = 0.0f;
#pragma unroll
    for (int m = 0; m < 6; ++m) {
        float X0 = t0[m],     X1 = t1[m],     X2 = t2[m];
        float Y0 = t0[m + 1], Y1 = t1[m + 1], Y2 = t2[m + 1];
        float Z0 = t0[m + 2], Z1 = t1[m + 2], Z2 = t2[m + 2];
        float xz0 = X0 + Z0, xz1 = X1 + Z1, xz2 = X2 + Z2;
        float d00 = k0 * (xz0 + Y0), d01 = k1 * (X0 - Z0), d02 = k2 * fmaf(-2.0f, Y0, xz0);
        float d10 = k0 * (xz1 + Y1), d11 = k1 * (X1 - Z1), d12 = k2 * fmaf(-2.0f, Y1, xz1);
        float d20 = k0 * (xz2 + Y2), d21 = k1 * (X2 - Z2), d22 = k2 * fmaf(-2.0f, Y2, xz2);

        float S1 = (std3_fast(d00, d01, d02) + std3_fast(d10, d11, d12) + std3_fast(d20, d21, d22)) * (1.0f / 3.0f);
        float S2 = (std3_fast(d00, d10, d20) + std3_fast(d01, d11, d21) + std3_fast(d02, d12, d22)) * (1.0f / 3.0f);
        float S3 = std3_fast(d00, d11, d22);
        float S4 = std3_fast(d02, d11, d20);

        float sumS = (S1 + S2) + (S3 + S4);
        float sumQ = fmaf(S1, S1, fmaf(S2, S2, fmaf(S3, S3, S4 * S4)));
        float h    = fmaxf(fmaf(-0.25f * sumS, sumS, sumQ), 0.0f);
        float Sm   = fmaf(sumS, 0.25f, 1e-8f);
        float inv  = frcp_fast(Sm);
        psi_run    = fmaf(h * inv * inv, (1.0f / 3.0f), psi_run);
    }
    return psi_run;
}

#define BIN4_1CH(V, COL) { \
        _Pragma("unroll") \
        for (int e_ = 0; e_ < 4; ++e_) { \
            float val_ = (&(V).x)[e_]; \
            int bin_ = (int)rintf(val_ * 255.0f);   /* round-half-even == np.round */ \
            bin_ = min(max(bin_, 0), 255); \
            int ce_ = (COL) + e_; \
            int p_  = (ce_ * 2341) >> 15;           /* ce/14 for ce<112 */ \
            atomicAdd(&hist[p_ >> 2][bin_], 1u << ((p_ & 3) * 8)); \
        }}

// ---------------- Kernel A: per patch-channel richness ----------------
__global__ __launch_bounds__(192, 8) void rich_pc_kernel(
    const float* __restrict__ x,
    const float* __restrict__ dctm,
    float* __restrict__ ws)
{
    const int bid = blockIdx.x;       // ch*2048 + (b*128 + hp*4 + wpg)
    const int ch  = bid >> 11;
    const int r_  = bid & 2047;
    const int wpg = r_ & 3;
    const int hp  = (r_ >> 2) & 31;
    const int b   = r_ >> 7;
    const int tid = threadIdx.x;

    __shared__ uint32 hist[2][256];   // 8 patches, u8 x4-packed (max count 196)
    __shared__ float  psiPart[8][24];
    __shared__ float  entAcc[8];

    const float k0 = dctm[0];
    const float k1 = dctm[3];
    const float k2 = dctm[6];

    for (int i = tid; i < 512; i += 192) ((uint32*)hist)[i] = 0u;
    __syncthreads();

    const size_t plane = ((size_t)(b * 3 + ch) * 448 + hp * 14) * 448 + wpg * 112;

    // run base: one 6-window half-row per thread
    const int pl   = tid / 24;        // 0..7 local patch
    const int rr   = tid - pl * 24;   // 0..23
    const int wi   = rr >> 1, half = rr & 1;
    const float* base = x + plane + (size_t)wi * 448 + pl * 14 + half * 6;

    // hist quads: plane has 14 rows x 28 float4 = 392 quads.
    // thread covers quad tid and tid+192 (0..383); tail 384..391 (row 13, rem 20..27).
    int row0 = tid / 28,  col0 = (tid - row0 * 28) * 4;
    int t1_  = tid + 192;
    int row1 = t1_ / 28,  col1 = (t1_ - row1 * 28) * 4;
    const float* src0 = x + plane + (size_t)row0 * 448 + col0;
    const float* src1 = x + plane + (size_t)row1 * 448 + col1;

    // pipelined: run loads + hist loads in flight together, then compute, then bin
    RunData rd = load_run(base);
    float4 h0 = *reinterpret_cast<const float4*>(src0);
    float4 h1 = *reinterpret_cast<const float4*>(src1);

    float psi = run_psi(rd, k0, k1, k2);
    psiPart[pl][rr] = psi;

    BIN4_1CH(h0, col0)
    BIN4_1CH(h1, col1)
    if (tid < 8) {                    // tail quads 384..391: row 13, cols (20+tid)*4
        int colT = (20 + tid) * 4;
        const float* srcT = x + plane + (size_t)13 * 448 + colT;
        float4 hT = *reinterpret_cast<const float4*>(srcT);
        BIN4_1CH(hT, colT)
    }
    __syncthreads();   // psiPart written AND hist atomics drained

    // entropy: 8 threads per patch, 32 bins each (wave 0 only)
    if (tid < 64) {
        const int pcE = tid >> 3, sub = tid & 7;
        const int rowW = pcE >> 2, sh = (pcE & 3) * 8;
        float negent = 0.0f;
#pragma unroll
        for (int kk = 0; kk < 32; ++kk) {
            uint32 c = (hist[rowW][sub + 8 * kk] >> sh) & 0xffu;
            float pr = (float)c * (1.0f / 196.0f) + 1e-10f;
            negent = fmaf(pr, flog2_fast(pr), negent);
        }
#pragma unroll
        for (int off = 1; off < 8; off <<= 1) negent += __shfl_xor(negent, off, 64);
        if (sub == 0) entAcc[pcE] = -negent;
    }
    __syncthreads();

    if (tid < 8) {
        float s = 0.0f;
#pragma unroll
        for (int r = 0; r < 24; ++r) s += psiPart[tid][r];
        ws[ch * 16384 + ((b * 32 + hp) * 32 + wpg * 8 + tid)] =
            (s * (1.0f / 144.0f)) * entAcc[tid];
    }
}

// ---------------- Kernel B: channel mean ----------------
__global__ __launch_bounds__(256) void combine_kernel(
    const float* __restrict__ ws, float* __restrict__ out)
{
    int i = blockIdx.x * 256 + threadIdx.x;   // 0..16383
    out[i] = (ws[i] + ws[16384 + i] + ws[32768 + i]) * (1.0f / 3.0f);
}

// ---------------- Fallback: r9 proven single-kernel (38.6us) ----------------
__global__ __launch_bounds__(192, 6) void richness_kernel(
    const float* __restrict__ x,
    const float* __restrict__ dctm,
    float* __restrict__ out)
{
    const int bid = blockIdx.x;       // b*128 + hp*4 + wpg
    const int wpg = bid & 3;
    const int hp  = (bid >> 2) & 31;
    const int b   = bid >> 7;
    const int tid = threadIdx.x;

    __shared__ uint32 hist[6][256];
    __shared__ float  psiPart[24][24];
    __shared__ float  entAcc[24];
    __shared__ float  richAcc[24];

    const float k0 = dctm[0];
    const float k1 = dctm[3];
    const float k2 = dctm[6];

    for (int i = tid; i < 6 * 256; i += 192) ((uint32*)hist)[i] = 0u;
    __syncthreads();

#define BIN4(V, CH, COL) { \
        _Pragma("unroll") \
        for (int e_ = 0; e_ < 4; ++e_) { \
            float val_ = (&(V).x)[e_]; \
            int bin_ = (int)rintf(val_ * 255.0f); \
            bin_ = min(max(bin_, 0), 255); \
            int ce_ = (COL) + e_; \
            int p_  = (ce_ * 2341) >> 15; \
            int pc_ = (CH) * 8 + p_; \
            atomicAdd(&hist[pc_ >> 2][bin_], 1u << ((pc_ & 3) * 8)); \
        }}

    for (int t = tid; t < 1176; t += 192) {
        int ch  = t / 392;
        int rem = t - ch * 392;
        int row = rem / 28;
        int col = (rem - row * 28) * 4;
        const float* src = x + (((size_t)(b * 3 + ch) * 448 + hp * 14 + row) * 448) + wpg * 112 + col;
        float4 v = *reinterpret_cast<const float4*>(src);
        BIN4(v, ch, col)
    }

#pragma unroll
    for (int kr = 0; kr < 3; ++kr) {
        int rho = tid + 192 * kr;
        int pc  = rho / 24;
        int rr  = rho - pc * 24;
        int ch = pc >> 3, p = pc & 7;
        int wi = rr >> 1, half = rr & 1;
        const float* base = x + (((size_t)(b * 3 + ch) * 448 + hp * 14 + wi) * 448)
                              + wpg * 112 + p * 14 + half * 6;
        RunData rd = load_run(base);
        psiPart[pc][rr] = run_psi(rd, k0, k1, k2);
    }
#undef BIN4
    __syncthreads();

    {
        const int pcE = tid >> 3, sub = tid & 7;
        const int rowW = pcE >> 2, sh = (pcE & 3) * 8;
        float negent = 0.0f;
#pragma unroll
        for (int kk = 0; kk < 32; ++kk) {
            uint32 c = (hist[rowW][sub + 8 * kk] >> sh) & 0xffu;
            float pr = (float)c * (1.0f / 196.0f) + 1e-10f;
            negent = fmaf(pr, flog2_fast(pr), negent);
        }
#pragma unroll
        for (int off = 1; off < 8; off <<= 1) negent += __shfl_xor(negent, off, 64);
        if (sub == 0) entAcc[pcE] = -negent;
    }
    __syncthreads();

    if (tid < 24) {
        float s = 0.0f;
#pragma unroll
        for (int r = 0; r < 24; ++r) s += psiPart[tid][r];
        richAcc[tid] = (s * (1.0f / 144.0f)) * entAcc[tid];
    }
    __syncthreads();

    if (tid < 8) {
        float rv = (richAcc[tid] + richAcc[8 + tid] + richAcc[16 + tid]) * (1.0f / 3.0f);
        out[(b * 32 + hp) * 32 + wpg * 8 + tid] = rv;
    }
}

extern "C" void kernel_launch(void* const* d_in, const int* in_sizes, int n_in,
                              void* d_out, int out_size, void* d_ws, size_t ws_size,
                              hipStream_t stream) {
    const float* x    = (const float*)d_in[0];
    const float* dctm = (const float*)d_in[1];
    float* out        = (float*)d_out;

    if (ws_size >= 49152 * sizeof(float) && d_ws != nullptr) {
        float* ws = (float*)d_ws;
        rich_pc_kernel<<<6144, 192, 0, stream>>>(x, dctm, ws);
        combine_kernel<<<64, 256, 0, stream>>>(ws, out);
    } else {
        richness_kernel<<<2048, 192, 0, stream>>>(x, dctm, out);
    }
}

// Round 12
// 39.995 us; speedup vs baseline: 1.0318x; 1.0318x over previous
//
#include <hip/hip_runtime.h>
#include <math.h>

// x: (16,3,448,448) fp32; 14x14 patches -> Hp=Wp=32; 3x3 DCT over 12x12 sliding windows
// out: (16,32,32) fp32
//
// TWO-KERNEL SPLIT (decouple memory-burst phase from compute phase):
//  Kernel A (psi_kernel): windows only. No LDS, no barriers, no histogram.
//    2048 blocks x 192 thr; thread = 3 half-row runs of 6 windows, all within ONE
//    pc (pc = tid>>3, 8 lanes x 3 runs = 24 runs = 144 windows); psi reduced by
//    8-lane shfl_xor; lane s==0 stores psi_mean to ws[ch*16384 + patch].
//    Pure streaming compute -> waves desynchronize, loads hide under other waves.
//  Kernel B (ent_kernel): r9's proven histogram+entropy path; multiplies by psi
//    from ws, channel-means into out. Memory-dominated, short.
// Fallback if ws too small: r9 single-kernel (38.6us, proven).

typedef unsigned int uint32;

__device__ __forceinline__ float fsqrt_fast(float x) { return __builtin_amdgcn_sqrtf(x); } // v_sqrt_f32
__device__ __forceinline__ float frcp_fast(float x)  { return __builtin_amdgcn_rcpf(x);  } // v_rcp_f32
__device__ __forceinline__ float flog2_fast(float x) { return __builtin_amdgcn_logf(x);  } // v_log_f32

__device__ __forceinline__ float std3_fast(float a, float b, float c) {
    // ddof=0 std of 3 via E[x^2]-E[x]^2 (clamped)
    float s = a + b + c;
    float q = fmaf(a, a, fmaf(b, b, c * c));
    float v = fmaf(q, (1.0f / 3.0f), (s * s) * (-1.0f / 9.0f));
    return fsqrt_fast(fmaxf(v, 0.0f));
}

struct RunData {
    float2 a0, a1, a2, a3, b0, b1, b2, b3, c0, c1, c2, c3;
};

__device__ __forceinline__ RunData load_run(const float* base) {
    RunData r;
    r.a0 = *reinterpret_cast<const float2*>(base + 0);
    r.a1 = *reinterpret_cast<const float2*>(base + 2);
    r.a2 = *reinterpret_cast<const float2*>(base + 4);
    r.a3 = *reinterpret_cast<const float2*>(base + 6);
    r.b0 = *reinterpret_cast<const float2*>(base + 448);
    r.b1 = *reinterpret_cast<const float2*>(base + 450);
    r.b2 = *reinterpret_cast<const float2*>(base + 452);
    r.b3 = *reinterpret_cast<const float2*>(base + 454);
    r.c0 = *reinterpret_cast<const float2*>(base + 896);
    r.c1 = *reinterpret_cast<const float2*>(base + 898);
    r.c2 = *reinterpret_cast<const float2*>(base + 900);
    r.c3 = *reinterpret_cast<const float2*>(base + 902);
    return r;
}

__device__ __forceinline__ float run_psi(const RunData& rd, float k0, float k1, float k2) {
    float r0[8] = { rd.a0.x, rd.a0.y, rd.a1.x, rd.a1.y, rd.a2.x, rd.a2.y, rd.a3.x, rd.a3.y };
    float r1[8] = { rd.b0.x, rd.b0.y, rd.b1.x, rd.b1.y, rd.b2.x, rd.b2.y, rd.b3.x, rd.b3.y };
    float r2[8] = { rd.c0.x, rd.c0.y, rd.c1.x, rd.c1.y, rd.c2.x, rd.c2.y, rd.c3.x, rd.c3.y };

    float t0[8], t1[8], t2[8];
#pragma unroll
    for (int J = 0; J < 8; ++J) {
        float s = r0[J] + r2[J];
        t0[J] = k0 * (s + r1[J]);
        t1[J] = k1 * (r0[J] - r2[J]);
        t2[J] = k2 * fmaf(-2.0f, r1[J], s);
    }

    float psi_run = 0.0f;
#pragma unroll
    for (int m = 0; m < 6; ++m) {
        float X0 = t0[m],     X1 = t1[m],     X2 = t2[m];
        float Y0 = t0[m + 1], Y1 = t1[m + 1], Y2 = t2[m + 1];
        float Z0 = t0[m + 2], Z1 = t1[m + 2], Z2 = t2[m + 2];
        float xz0 = X0 + Z0, xz1 = X1 + Z1, xz2 = X2 + Z2;
        float d00 = k0 * (xz0 + Y0), d01 = k1 * (X0 - Z0), d02 = k2 * fmaf(-2.0f, Y0, xz0);
        float d10 = k0 * (xz1 + Y1), d11 = k1 * (X1 - Z1), d12 = k2 * fmaf(-2.0f, Y1, xz1);
        float d20 = k0 * (xz2 + Y2), d21 = k1 * (X2 - Z2), d22 = k2 * fmaf(-2.0f, Y2, xz2);

        float S1 = (std3_fast(d00, d01, d02) + std3_fast(d10, d11, d12) + std3_fast(d20, d21, d22)) * (1.0f / 3.0f);
        float S2 = (std3_fast(d00, d10, d20) + std3_fast(d01, d11, d21) + std3_fast(d02, d12, d22)) * (1.0f / 3.0f);
        float S3 = std3_fast(d00, d11, d22);
        float S4 = std3_fast(d02, d11, d20);

        float sumS = (S1 + S2) + (S3 + S4);
        float sumQ = fmaf(S1, S1, fmaf(S2, S2, fmaf(S3, S3, S4 * S4)));
        float h    = fmaxf(fmaf(-0.25f * sumS, sumS, sumQ), 0.0f);
        float Sm   = fmaf(sumS, 0.25f, 1e-8f);
        float inv  = frcp_fast(Sm);
        psi_run    = fmaf(h * inv * inv, (1.0f / 3.0f), psi_run);
    }
    return psi_run;
}

// ---------------- Kernel A: psi only (no LDS, no barriers) ----------------
__global__ __launch_bounds__(192, 4) void psi_kernel(
    const float* __restrict__ x,
    const float* __restrict__ dctm,
    float* __restrict__ ws)
{
    const int bid = blockIdx.x;       // b*128 + hp*4 + wpg
    const int wpg = bid & 3;
    const int hp  = (bid >> 2) & 31;
    const int b   = bid >> 7;
    const int tid = threadIdx.x;

    const float k0 = dctm[0];
    const float k1 = dctm[3];
    const float k2 = dctm[6];

    const int pc = tid >> 3;          // 0..23
    const int s  = tid & 7;           // 0..7
    const int ch = pc >> 3, pl = pc & 7;

    const float* pb = x + (((size_t)(b * 3 + ch) * 448 + hp * 14) * 448) + wpg * 112 + pl * 14;

    // runs rj = s + 8*kr, kr = 0..2 (all 24 runs of this pc covered by its 8 lanes)
    const int rj0 = s,      wi0 = rj0 >> 1, hf0 = rj0 & 1;
    const int rj1 = s + 8,  wi1 = rj1 >> 1, hf1 = rj1 & 1;
    const int rj2 = s + 16, wi2 = rj2 >> 1, hf2 = rj2 & 1;

    // staggered loads: rd0, rd1 in flight; compute rd0; load rd2 under rd1's compute
    RunData rd0 = load_run(pb + (size_t)wi0 * 448 + hf0 * 6);
    RunData rd1 = load_run(pb + (size_t)wi1 * 448 + hf1 * 6);
    float psi = run_psi(rd0, k0, k1, k2);
    RunData rd2 = load_run(pb + (size_t)wi2 * 448 + hf2 * 6);
    psi += run_psi(rd1, k0, k1, k2);
    psi += run_psi(rd2, k0, k1, k2);

    // 8-lane reduction within the pc's lane octet
    psi += __shfl_xor(psi, 1, 64);
    psi += __shfl_xor(psi, 2, 64);
    psi += __shfl_xor(psi, 4, 64);

    if (s == 0)
        ws[ch * 16384 + ((b * 32 + hp) * 32 + wpg * 8 + pl)] = psi * (1.0f / 144.0f);
}

// ---------------- Kernel B: histogram + entropy + combine ----------------
__global__ __launch_bounds__(192, 8) void ent_kernel(
    const float* __restrict__ x,
    const float* __restrict__ ws,
    float* __restrict__ out)
{
    const int bid = blockIdx.x;       // b*128 + hp*4 + wpg
    const int wpg = bid & 3;
    const int hp  = (bid >> 2) & 31;
    const int b   = bid >> 7;
    const int tid = threadIdx.x;

    __shared__ uint32 hist[6][256];   // 24 pcs, u8 x4-packed (max count 196, no carry)
    __shared__ float  entAcc[24];

    for (int i = tid; i < 6 * 256; i += 192) ((uint32*)hist)[i] = 0u;
    __syncthreads();

    for (int t = tid; t < 1176; t += 192) {          // 3ch * 14 rows * 28 float4
        int ch  = t / 392;
        int rem = t - ch * 392;
        int row = rem / 28;
        int col = (rem - row * 28) * 4;
        const float* src = x + (((size_t)(b * 3 + ch) * 448 + hp * 14 + row) * 448) + wpg * 112 + col;
        float4 v = *reinterpret_cast<const float4*>(src);
#pragma unroll
        for (int e = 0; e < 4; ++e) {
            float val = (&v.x)[e];
            int bin = (int)rintf(val * 255.0f);      // round-half-even == np.round
            bin = min(max(bin, 0), 255);
            int ce = col + e;
            int p  = (ce * 2341) >> 15;              // ce/14 for ce<112
            int pc = ch * 8 + p;
            atomicAdd(&hist[pc >> 2][bin], 1u << ((pc & 3) * 8));
        }
    }
    __syncthreads();

    // entropy: 8 threads per pc, 32 bins each
    {
        const int pcE = tid >> 3, sub = tid & 7;
        const int rowW = pcE >> 2, sh = (pcE & 3) * 8;
        float negent = 0.0f;
#pragma unroll
        for (int kk = 0; kk < 32; ++kk) {
            uint32 c = (hist[rowW][sub + 8 * kk] >> sh) & 0xffu;
            float pr = (float)c * (1.0f / 196.0f) + 1e-10f;
            negent = fmaf(pr, flog2_fast(pr), negent);
        }
#pragma unroll
        for (int off = 1; off < 8; off <<= 1) negent += __shfl_xor(negent, off, 64);
        if (sub == 0) entAcc[pcE] = -negent;
    }
    __syncthreads();

    // combine: tid<8 = local patch; mean over channels of psi*entropy
    if (tid < 8) {
        int pidx = (b * 32 + hp) * 32 + wpg * 8 + tid;
        float rv = (ws[pidx]         * entAcc[tid] +
                    ws[16384 + pidx] * entAcc[8 + tid] +
                    ws[32768 + pidx] * entAcc[16 + tid]) * (1.0f / 3.0f);
        out[pidx] = rv;
    }
}

// ---------------- Fallback: r9 proven single-kernel (38.6us) ----------------
__global__ __launch_bounds__(192, 6) void richness_kernel(
    const float* __restrict__ x,
    const float* __restrict__ dctm,
    float* __restrict__ out)
{
    const int bid = blockIdx.x;
    const int wpg = bid & 3;
    const int hp  = (bid >> 2) & 31;
    const int b   = bid >> 7;
    const int tid = threadIdx.x;

    __shared__ uint32 hist[6][256];
    __shared__ float  psiPart[24][24];
    __shared__ float  entAcc[24];
    __shared__ float  richAcc[24];

    const float k0 = dctm[0];
    const float k1 = dctm[3];
    const float k2 = dctm[6];

    for (int i = tid; i < 6 * 256; i += 192) ((uint32*)hist)[i] = 0u;
    __syncthreads();

    for (int t = tid; t < 1176; t += 192) {
        int ch  = t / 392;
        int rem = t - ch * 392;
        int row = rem / 28;
        int col = (rem - row * 28) * 4;
        const float* src = x + (((size_t)(b * 3 + ch) * 448 + hp * 14 + row) * 448) + wpg * 112 + col;
        float4 v = *reinterpret_cast<const float4*>(src);
#pragma unroll
        for (int e = 0; e < 4; ++e) {
            float val = (&v.x)[e];
            int bin = (int)rintf(val * 255.0f);
            bin = min(max(bin, 0), 255);
            int ce = col + e;
            int p  = (ce * 2341) >> 15;
            int pc = ch * 8 + p;
            atomicAdd(&hist[pc >> 2][bin], 1u << ((pc & 3) * 8));
        }
    }

#pragma unroll
    for (int kr = 0; kr < 3; ++kr) {
        int rho = tid + 192 * kr;
        int pc  = rho / 24;
        int rr  = rho - pc * 24;
        int ch = pc >> 3, p = pc & 7;
        int wi = rr >> 1, half = rr & 1;
        const float* base = x + (((size_t)(b * 3 + ch) * 448 + hp * 14 + wi) * 448)
                              + wpg * 112 + p * 14 + half * 6;
        RunData rd = load_run(base);
        psiPart[pc][rr] = run_psi(rd, k0, k1, k2);
    }
    __syncthreads();

    {
        const int pcE = tid >> 3, sub = tid & 7;
        const int rowW = pcE >> 2, sh = (pcE & 3) * 8;
        float negent = 0.0f;
#pragma unroll
        for (int kk = 0; kk < 32; ++kk) {
            uint32 c = (hist[rowW][sub + 8 * kk] >> sh) & 0xffu;
            float pr = (float)c * (1.0f / 196.0f) + 1e-10f;
            negent = fmaf(pr, flog2_fast(pr), negent);
        }
#pragma unroll
        for (int off = 1; off < 8; off <<= 1) negent += __shfl_xor(negent, off, 64);
        if (sub == 0) entAcc[pcE] = -negent;
    }
    __syncthreads();

    if (tid < 24) {
        float s = 0.0f;
#pragma unroll
        for (int r = 0; r < 24; ++r) s += psiPart[tid][r];
        richAcc[tid] = (s * (1.0f / 144.0f)) * entAcc[tid];
    }
    __syncthreads();

    if (tid < 8) {
        float rv = (richAcc[tid] + richAcc[8 + tid] + richAcc[16 + tid]) * (1.0f / 3.0f);
        out[(b * 32 + hp) * 32 + wpg * 8 + tid] = rv;
    }
}

extern "C" void kernel_launch(void* const* d_in, const int* in_sizes, int n_in,
                              void* d_out, int out_size, void* d_ws, size_t ws_size,
                              hipStream_t stream) {
    const float* x    = (const float*)d_in[0];
    const float* dctm = (const float*)d_in[1];
    float* out        = (float*)d_out;

    if (ws_size >= 49152 * sizeof(float) && d_ws != nullptr) {
        float* ws = (float*)d_ws;
        psi_kernel<<<2048, 192, 0, stream>>>(x, dctm, ws);
        ent_kernel<<<2048, 192, 0, stream>>>(x, ws, out);
    } else {
        richness_kernel<<<2048, 192, 0, stream>>>(x, dctm, out);
    }
}